// Round 1
// baseline (466.290 us; speedup 1.0000x reference)
//
#include <hip/hip_runtime.h>
#include <hip/hip_bf16.h>

#define BB 256      // batches
#define P 64        // cluster dim
#define MM 4096     // samples per row
#define MC 128      // chunk columns for cov staging
#define MT 256      // tile columns for apply

// ---------------- Kernel A: partial sums for covariance ----------------
// grid (BB, nsplit), block 64 threads (1 wave). 8x8 register blocking with
// row-interleaved assignment (rows br+8i, cols bc+8k) so the per-m float4
// LDS reads hit 8 distinct banks (conflict-free broadcasts).
__global__ __launch_bounds__(64)
void covpart_kernel(const float* __restrict__ x, float* __restrict__ s2p,
                    float* __restrict__ s1p, int nsplit)
{
    __shared__ __align__(16) float Xs[P][MC + 4];   // [c][m], stride 132 words
    const int b = blockIdx.x, sp = blockIdx.y;
    const int t = threadIdx.x;
    const int mlen = MM / nsplit;
    const float* xb = x + (size_t)b * (P * MM) + (size_t)sp * mlen;
    const int br = t >> 3, bc = t & 7;

    float acc[8][8];
    #pragma unroll
    for (int i = 0; i < 8; ++i)
        #pragma unroll
        for (int k = 0; k < 8; ++k) acc[i][k] = 0.f;
    float s1[8] = {0.f,0.f,0.f,0.f,0.f,0.f,0.f,0.f};

    const int nch = mlen / MC;
    for (int ch = 0; ch < nch; ++ch) {
        const int m0 = ch * MC;
        __syncthreads();
        #pragma unroll
        for (int j = 0; j < 32; ++j) {
            int f = 4 * (t + 64 * j);       // flat float index into 64x128 tile
            int r = f >> 7;
            int c = f & 127;
            float4 v = *reinterpret_cast<const float4*>(xb + (size_t)r * MM + m0 + c);
            *reinterpret_cast<float4*>(&Xs[r][c]) = v;
        }
        __syncthreads();
        for (int mg = 0; mg < MC; mg += 4) {
            float a[8][4], bv[8][4];
            #pragma unroll
            for (int i = 0; i < 8; ++i)
                *reinterpret_cast<float4*>(a[i]) =
                    *reinterpret_cast<const float4*>(&Xs[br + 8 * i][mg]);
            #pragma unroll
            for (int k = 0; k < 8; ++k)
                *reinterpret_cast<float4*>(bv[k]) =
                    *reinterpret_cast<const float4*>(&Xs[bc + 8 * k][mg]);
            #pragma unroll
            for (int i = 0; i < 8; ++i)
                #pragma unroll
                for (int k = 0; k < 8; ++k)
                    acc[i][k] += a[i][0] * bv[k][0] + a[i][1] * bv[k][1]
                               + a[i][2] * bv[k][2] + a[i][3] * bv[k][3];
            if (bc == 0) {
                #pragma unroll
                for (int i = 0; i < 8; ++i)
                    s1[i] += a[i][0] + a[i][1] + a[i][2] + a[i][3];
            }
        }
    }
    float* s2b = s2p + ((size_t)sp * BB + b) * (P * P);
    #pragma unroll
    for (int i = 0; i < 8; ++i)
        #pragma unroll
        for (int k = 0; k < 8; ++k)
            s2b[(br + 8 * i) * P + (bc + 8 * k)] = acc[i][k];
    if (bc == 0) {
        float* s1b = s1p + ((size_t)sp * BB + b) * P;
        #pragma unroll
        for (int i = 0; i < 8; ++i) s1b[br + 8 * i] = s1[i];
    }
}

// ---------------- Kernel B: shrinkage + Newton-Schulz inverse sqrt ----------------
typedef float (*Mat68)[68];

// D = alpha * (A^T * B) + beta * I ; A symmetric => A^T*B == A*B.
// Column reads of A become contiguous row reads via symmetry (float4).
__device__ inline void mm64f(Mat68 D, Mat68 A, Mat68 Bm, int t, float alpha, float beta)
{
    __syncthreads();
    const int r0 = (t >> 4) * 4, c0 = (t & 15) * 4;
    float acc[4][4];
    #pragma unroll
    for (int i = 0; i < 4; ++i)
        #pragma unroll
        for (int j = 0; j < 4; ++j) acc[i][j] = 0.f;
    #pragma unroll 4
    for (int k = 0; k < P; ++k) {
        float av[4], bv[4];
        *reinterpret_cast<float4*>(av) = *reinterpret_cast<const float4*>(&A[k][r0]);
        *reinterpret_cast<float4*>(bv) = *reinterpret_cast<const float4*>(&Bm[k][c0]);
        #pragma unroll
        for (int i = 0; i < 4; ++i)
            #pragma unroll
            for (int j = 0; j < 4; ++j) acc[i][j] += av[i] * bv[j];
    }
    __syncthreads();
    #pragma unroll
    for (int i = 0; i < 4; ++i)
        #pragma unroll
        for (int j = 0; j < 4; ++j)
            D[r0 + i][c0 + j] = alpha * acc[i][j] + ((r0 + i) == (c0 + j) ? beta : 0.f);
}

__global__ __launch_bounds__(256)
void whiten_kernel(const float* __restrict__ s2p, const float* __restrict__ s1p,
                   float* __restrict__ shat, float* __restrict__ tvec, int nsplit)
{
    __shared__ __align__(16) float B0[P][68], B1[P][68], B2[P][68], B3[P][68], B4[P][68];
    __shared__ float mus[P];
    __shared__ float red[2][4];
    const int b = blockIdx.x, t = threadIdx.x;

    if (t < P) {
        float s = 0.f;
        for (int sp = 0; sp < nsplit; ++sp) s += s1p[((size_t)sp * BB + b) * P + t];
        mus[t] = s * (1.0f / MM);
    }
    __syncthreads();

    // assemble C = S2/M - mu mu^T into B0; accumulate trace and tr(C^2)
    float tr_part = 0.f, s2_part = 0.f;
    #pragma unroll
    for (int j = 0; j < 16; ++j) {
        int f = t + 256 * j;
        int i = f >> 6, jc = f & 63;
        float sum = 0.f;
        for (int sp = 0; sp < nsplit; ++sp)
            sum += s2p[((size_t)sp * BB + b) * (P * P) + f];
        float v = sum * (1.0f / MM) - mus[i] * mus[jc];
        B0[i][jc] = v;
        s2_part += v * v;
        if (i == jc) tr_part += v;
    }
    #pragma unroll
    for (int off = 32; off > 0; off >>= 1) {
        tr_part += __shfl_down(tr_part, off);
        s2_part += __shfl_down(s2_part, off);
    }
    if ((t & 63) == 0) { red[0][t >> 6] = tr_part; red[1][t >> 6] = s2_part; }
    __syncthreads();
    const float trace = red[0][0] + red[0][1] + red[0][2] + red[0][3];
    const float sum2  = red[1][0] + red[1][1] + red[1][2] + red[1][3];

    const float nf = (float)MM;
    const float num = (nf - 2.0f) / nf * sum2 + trace * trace;
    const float den = (nf + 2.0f) * (sum2 - trace * trace / (float)P);
    const float rho = (den > 0.f) ? fminf(num / den, 1.0f) : 1.0f;
    const float lam = trace * (1.0f / P);      // mean eigenvalue (preserved by shrinkage)
    const float inv_s = 1.0f / lam;

    // B0 := A = C_shrunk/lam (spectrum ~ [0.75,1.3] -> NS-safe); B2 := T1 = 1.5I - 0.5A
    #pragma unroll
    for (int j = 0; j < 16; ++j) {
        int f = t + 256 * j;
        int i = f >> 6, jc = f & 63;
        float v = B0[i][jc];
        float sv = ((1.0f - rho) * v + ((i == jc) ? rho * lam : 0.f)) * inv_s;
        B0[i][jc] = sv;
        B2[i][jc] = ((i == jc) ? 1.5f : 0.f) - 0.5f * sv;
    }

    // Newton-Schulz: Y0=A, Z0=I (iter1 folded analytically: Z1=T1, Y1=A*T1)
    mm64f(B1, B0, B2, t, 1.f, 0.f);
    Mat68 Yc = B1, Zc = B2, Tc = B0, U = B3, V = B4;
    #pragma unroll
    for (int it = 0; it < 3; ++it) {
        mm64f(Tc, Zc, Yc, t, -0.5f, 1.5f);   // T = 1.5I - 0.5 Z*Y
        mm64f(U,  Yc, Tc, t, 1.f, 0.f);      // Y' = Y*T
        mm64f(V,  Tc, Zc, t, 1.f, 0.f);      // Z' = T*Z
        Mat68 tmp = Yc; Yc = U; U = tmp;
        tmp = Zc; Zc = V; V = tmp;
    }
    mm64f(Tc, Zc, Yc, t, -0.5f, 1.5f);       // final half-step (only Z needed)
    mm64f(U,  Tc, Zc, t, 1.f, 0.f);          // U = A^{-1/2}
    __syncthreads();

    const float sc = rsqrtf(lam);            // C_shrunk^{-1/2} = A^{-1/2}/sqrt(lam)
    float* sb = shat + (size_t)b * (P * P);
    #pragma unroll
    for (int j = 0; j < 16; ++j) {
        int f = t + 256 * j;
        int i = f >> 6, jc = f & 63;
        sb[f] = U[i][jc] * sc;
    }
    if (t < P) {
        float tv = 0.f;
        #pragma unroll
        for (int d = 0; d < P; ++d) tv += U[t][d] * mus[d];
        tvec[b * P + t] = tv * sc;
    }
}

// ---------------- Kernel C: Z = S_hat * x - (S_hat mu) ----------------
// grid (MM/MT, BB), block 256. LDS = 16KB S + 64KB X tile = 80KB (2 blocks/CU).
__global__ __launch_bounds__(256)
void apply_kernel(const float* __restrict__ x, const float* __restrict__ shat,
                  const float* __restrict__ tvec, float* __restrict__ out)
{
    __shared__ __align__(16) float Ss[P][P];
    __shared__ __align__(16) float Xs[P][MT];
    const int mt = blockIdx.x, b = blockIdx.y;
    const int t = threadIdx.x;
    const float* xb = x + (size_t)b * (P * MM) + mt * MT;
    const float* sb = shat + (size_t)b * (P * P);

    #pragma unroll
    for (int j = 0; j < 4; ++j) {
        int f4 = t + 256 * j;                  // 1024 float4s of S
        int i = f4 >> 4;
        int c = (f4 & 15) * 4;
        *reinterpret_cast<float4*>(&Ss[i][c]) =
            *reinterpret_cast<const float4*>(sb + (size_t)f4 * 4);
    }
    #pragma unroll
    for (int j = 0; j < 16; ++j) {
        int f4 = t + 256 * j;                  // 4096 float4s of X tile
        int r = f4 >> 6;
        int c = (f4 & 63) * 4;
        *reinterpret_cast<float4*>(&Xs[r][c]) =
            *reinterpret_cast<const float4*>(xb + (size_t)r * MM + c);
    }
    __syncthreads();

    const int cg = t >> 4, mg = t & 15;
    const int r0 = cg * 4;
    float acc[4][4][4];
    #pragma unroll
    for (int i = 0; i < 4; ++i)
        #pragma unroll
        for (int q = 0; q < 4; ++q)
            #pragma unroll
            for (int jj = 0; jj < 4; ++jj) acc[i][q][jj] = 0.f;

    for (int d = 0; d < P; ++d) {
        float sv[4];
        *reinterpret_cast<float4*>(sv) = *reinterpret_cast<const float4*>(&Ss[d][r0]); // S sym
        float xv[4][4];
        #pragma unroll
        for (int q = 0; q < 4; ++q)
            *reinterpret_cast<float4*>(xv[q]) =
                *reinterpret_cast<const float4*>(&Xs[d][q * 64 + mg * 4]);
        #pragma unroll
        for (int i = 0; i < 4; ++i)
            #pragma unroll
            for (int q = 0; q < 4; ++q)
                #pragma unroll
                for (int jj = 0; jj < 4; ++jj)
                    acc[i][q][jj] += sv[i] * xv[q][jj];
    }

    float* ob = out + (size_t)b * (P * MM) + mt * MT;
    #pragma unroll
    for (int i = 0; i < 4; ++i) {
        float tv = tvec[b * P + r0 + i];
        #pragma unroll
        for (int q = 0; q < 4; ++q) {
            float4 v = make_float4(acc[i][q][0] - tv, acc[i][q][1] - tv,
                                   acc[i][q][2] - tv, acc[i][q][3] - tv);
            *reinterpret_cast<float4*>(ob + (size_t)(r0 + i) * MM + q * 64 + mg * 4) = v;
        }
    }
}

extern "C" void kernel_launch(void* const* d_in, const int* in_sizes, int n_in,
                              void* d_out, int out_size, void* d_ws, size_t ws_size,
                              hipStream_t stream)
{
    const float* x = (const float*)d_in[0];
    float* out = (float*)d_out;

    // scratch layout (floats): s2p[ns][B][64][64] | s1p[ns][B][64] | shat[B][64][64] | tvec[B][64]
    auto need = [](int ns) -> size_t {
        return ((size_t)ns * BB * P * P + (size_t)ns * BB * P
                + (size_t)BB * P * P + (size_t)BB * P) * sizeof(float);
    };
    int nsplit = 4;
    if (ws_size < need(4)) nsplit = 2;
    if (ws_size < need(2)) nsplit = 1;

    float* s2p  = (float*)d_ws;
    float* s1p  = s2p + (size_t)nsplit * BB * P * P;
    float* shat = s1p + (size_t)nsplit * BB * P;
    float* tvec = shat + (size_t)BB * P * P;

    covpart_kernel<<<dim3(BB, nsplit), 64, 0, stream>>>(x, s2p, s1p, nsplit);
    whiten_kernel<<<dim3(BB), 256, 0, stream>>>(s2p, s1p, shat, tvec, nsplit);
    apply_kernel<<<dim3(MM / MT, BB), 256, 0, stream>>>(x, shat, tvec, out);
}